// Round 11
// baseline (17.348 us; speedup 1.0000x reference)
//
#include <hip/hip_runtime.h>
#include <math.h>

#define N_G   2048
#define W_IMG 128
#define H_IMG 128
#define NPIX  (W_IMG * H_IMG)
#define TANX  0.5f
#define TANY  0.5f
#define ALPHA_MIN (1.0f / 255.0f)
#define T_EPS_C 1e-4f
#define NTHR  1024
#define NWAVE 16
#define CAP   1024

// Kernel 1: full preprocess ONCE per gaussian (was 256x redundant when fused).
// Writes SoA: bb4=(px,py,ex,ey exact alpha-extents), f1=(conA,conB,conC,op_eff),
// f2=(cr,cg,cb,tz), radii direct to out.
__global__ __launch_bounds__(64) void gs_pre(const float* __restrict__ means3D,
                                             const float* __restrict__ opac,
                                             const float* __restrict__ colors,
                                             const float* __restrict__ scales,
                                             const float* __restrict__ rots,
                                             const float* __restrict__ viewm,
                                             const float* __restrict__ projm,
                                             float4* __restrict__ bb4,
                                             float4* __restrict__ f1g,
                                             float4* __restrict__ f2g,
                                             float* __restrict__ radii_out) {
    int i = blockIdx.x * 64 + threadIdx.x;
    if (i >= N_G) return;

    float mx = means3D[i * 3 + 0], my = means3D[i * 3 + 1], mz = means3D[i * 3 + 2];
    float pv0 = mx * viewm[0] + my * viewm[4] + mz * viewm[8]  + viewm[12];
    float pv1 = mx * viewm[1] + my * viewm[5] + mz * viewm[9]  + viewm[13];
    float tz  = mx * viewm[2] + my * viewm[6] + mz * viewm[10] + viewm[14];

    float ph[4];
#pragma unroll
    for (int j = 0; j < 4; j++)
        ph[j] = mx * projm[0 * 4 + j] + my * projm[1 * 4 + j] + mz * projm[2 * 4 + j] + projm[3 * 4 + j];
    float inv_w = __builtin_amdgcn_rcpf(ph[3] + 1e-7f);
    float ppx = ph[0] * inv_w, ppy = ph[1] * inv_w;

    float qr = rots[i * 4 + 0], qx = rots[i * 4 + 1], qy = rots[i * 4 + 2], qz = rots[i * 4 + 3];
    float qn = __builtin_amdgcn_rsqf(qr * qr + qx * qx + qy * qy + qz * qz);
    qr *= qn; qx *= qn; qy *= qn; qz *= qn;
    float R[3][3] = {
        {1.0f - 2.0f * (qy * qy + qz * qz), 2.0f * (qx * qy - qr * qz), 2.0f * (qx * qz + qr * qy)},
        {2.0f * (qx * qy + qr * qz), 1.0f - 2.0f * (qx * qx + qz * qz), 2.0f * (qy * qz - qr * qx)},
        {2.0f * (qx * qz - qr * qy), 2.0f * (qy * qz + qr * qx), 1.0f - 2.0f * (qx * qx + qy * qy)}};

    float sc[3] = {scales[i * 3 + 0], scales[i * 3 + 1], scales[i * 3 + 2]};
    float M[3][3];
#pragma unroll
    for (int r = 0; r < 3; r++)
#pragma unroll
        for (int cx = 0; cx < 3; cx++) M[r][cx] = R[r][cx] * sc[cx];

    float Sg[3][3];
#pragma unroll
    for (int r = 0; r < 3; r++)
#pragma unroll
        for (int kk = 0; kk < 3; kk++)
            Sg[r][kk] = M[r][0] * M[kk][0] + M[r][1] * M[kk][1] + M[r][2] * M[kk][2];

    float T1[3][3];
#pragma unroll
    for (int j = 0; j < 3; j++)
#pragma unroll
        for (int l = 0; l < 3; l++)
            T1[j][l] = Sg[j][0] * viewm[0 * 4 + l] + Sg[j][1] * viewm[1 * 4 + l] + Sg[j][2] * viewm[2 * 4 + l];
    float Cc[3][3];
#pragma unroll
    for (int r = 0; r < 3; r++)
#pragma unroll
        for (int l = 0; l < 3; l++)
            Cc[r][l] = viewm[0 * 4 + r] * T1[0][l] + viewm[1 * 4 + r] * T1[1][l] + viewm[2 * 4 + r] * T1[2][l];

    const float fx = W_IMG / (2.0f * TANX), fy = H_IMG / (2.0f * TANY);
    float invtz = __builtin_amdgcn_rcpf(tz);
    float txl = fminf(fmaxf(pv0 * invtz, -1.3f * TANX), 1.3f * TANX) * tz;
    float tyl = fminf(fmaxf(pv1 * invtz, -1.3f * TANY), 1.3f * TANY) * tz;
    float a0 = fx * invtz, a2 = -fx * txl * invtz * invtz;
    float b1 = fy * invtz, b2 = -fy * tyl * invtz * invtz;

    float c00 = a0 * a0 * Cc[0][0] + 2.0f * a0 * a2 * Cc[0][2] + a2 * a2 * Cc[2][2];
    float c11 = b1 * b1 * Cc[1][1] + 2.0f * b1 * b2 * Cc[1][2] + b2 * b2 * Cc[2][2];
    float c01 = a0 * b1 * Cc[0][1] + a0 * b2 * Cc[0][2] + a2 * b1 * Cc[1][2] + a2 * b2 * Cc[2][2];

    float a = c00 + 0.3f, c = c11 + 0.3f, b = c01;
    float det = a * c - b * b;
    bool valid = (tz > 0.2f) && (det > 0.0f);
    float det_s = (det > 0.0f) ? det : 1.0f;
    float rdet = __builtin_amdgcn_rcpf(det_s);
    float conA = c * rdet, conB = -b * rdet, conC = a * rdet;
    float mid = 0.5f * (a + c);
    float lam = mid + __builtin_amdgcn_sqrtf(fmaxf(0.1f, mid * mid - det));
    float radf = valid ? ceilf(3.0f * __builtin_amdgcn_sqrtf(lam)) : 0.0f;

    float op = opac[i];
    // alpha >= 1/255 requires d^T conic d <= 2L, L = log(255*op);
    // exact ellipse extents: |dx| <= sqrt(2L*a), |dy| <= sqrt(2L*c).
    float L = __logf(255.0f * op);
    float ex, ey;
    if (valid && L > 0.0f) {
        ex = __builtin_amdgcn_sqrtf(2.0f * L * a) + 2e-2f;
        ey = __builtin_amdgcn_sqrtf(2.0f * L * c) + 2e-2f;
    } else {
        ex = -1e9f; ey = -1e9f;
    }

    bb4[i] = make_float4(((ppx + 1.0f) * (float)W_IMG - 1.0f) * 0.5f,
                         ((ppy + 1.0f) * (float)H_IMG - 1.0f) * 0.5f, ex, ey);
    f1g[i] = make_float4(conA, conB, conC, valid ? op : 0.0f);
    f2g[i] = make_float4(colors[i * 3 + 0], colors[i * 3 + 1], colors[i * 3 + 2], tz);
    radii_out[i] = (float)(int)radf;
}

// Kernel 2: one block per 8x8 tile, 1024 threads = 4 waves/SIMD, 64 KB LDS.
// Phase A: cull from global bb4 (L2-broadcast stream, exact extents).
// Phase B: stable sort candidates by (tz, idx); gather params into sorted LDS SoA.
// Phase C: segmented composite over 16 waves (exact two-pass prefix products).
__global__ __launch_bounds__(NTHR) void gs_render(const float4* __restrict__ bb4,
                                                  const float4* __restrict__ f1g,
                                                  const float4* __restrict__ f2g,
                                                  const float* __restrict__ bg,
                                                  float* __restrict__ out) {
    __shared__ unsigned short lst[N_G];    // cull list; cnt overlay    4 KB
    __shared__ float4 scratch4[256];       // stz | Tseg                4 KB
    __shared__ float4 sf1[CAP];            // sorted conic+op          16 KB
    __shared__ float4 sf2[CAP];            // sorted color+tz          16 KB
    __shared__ float2 spos[CAP];           // sorted px,py              8 KB
    __shared__ float4 accv[NTHR];          // pass-B partials          16 KB
    __shared__ int s_count;

    float* scr = (float*)scratch4;
    int tid = threadIdx.x;
    int bid = blockIdx.x;
    if (tid == 0) s_count = 0;
    __syncthreads();

    int tilex = bid & 15, tiley = bid >> 4;
    int wave = tid >> 6, lane = tid & 63;

    // ---- Phase A: cull on exact extents, 16 waves x 2 chunks ----
    {
        float tx0 = (float)(tilex << 3), ty0 = (float)(tiley << 3);
        float tx1 = tx0 + 7.0f, ty1 = ty0 + 7.0f;
#pragma unroll
        for (int cc = 0; cc < 2; cc++) {
            int gi = (wave * 2 + cc) * 64 + lane;
            float4 b = bb4[gi];
            bool pred = (b.x >= tx0 - b.z) && (b.x <= tx1 + b.z) &&
                        (b.y >= ty0 - b.w) && (b.y <= ty1 + b.w);
            unsigned long long m = __ballot(pred);
            int n = (int)__popcll(m);
            int base = 0;
            if (lane == 0 && n) base = atomicAdd(&s_count, n);
            base = __shfl(base, 0);
            if (pred)
                lst[base + (int)__popcll(m & ((1ull << lane) - 1ull))] = (unsigned short)gi;
        }
    }
    __syncthreads();
    int c = min(s_count, CAP);

    // ---- Phase B1: gather candidate depths ----
    for (int t = tid; t < c; t += NTHR) scr[t] = f2g[lst[t]].w;
    __syncthreads();

    // ---- Phase B2: rank by (tz, idx); gather params into sorted LDS SoA ----
    for (int t = tid; t < c; t += NTHR) {
        int gi = lst[t];
        float my = scr[t];
        int rank = 0;
        int j = 0;
        for (; j + 4 <= c; j += 4) {
            float4 v = scratch4[j >> 2];
            int i0 = lst[j], i1 = lst[j + 1], i2 = lst[j + 2], i3 = lst[j + 3];
            rank += (v.x < my) || (v.x == my && i0 < gi);
            rank += (v.y < my) || (v.y == my && i1 < gi);
            rank += (v.z < my) || (v.z == my && i2 < gi);
            rank += (v.w < my) || (v.w == my && i3 < gi);
        }
        for (; j < c; j++) {
            float v = scr[j];
            rank += (v < my) || (v == my && lst[j] < gi);
        }
        sf1[rank] = f1g[gi];
        sf2[rank] = f2g[gi];
        float4 b = bb4[gi];
        spos[rank] = make_float2(b.x, b.y);
    }
    __syncthreads();   // scr (stz) dead; reused as Tseg

    // ---- Phase C: segmented composite over 16 waves ----
    float gx = (float)((tilex << 3) + (lane & 7));
    float gy = (float)((tiley << 3) + (lane >> 3));
    int seglen = (c + NWAVE - 1) / NWAVE;
    int s0 = wave * seglen;
    int s1 = min(c, s0 + seglen);

    // Pass A: per-segment transmittance product (alpha-only; matches cumprod)
    float Tw = 1.0f;
    for (int t = s0; t < s1; ++t) {
        float4 f1 = sf1[t];
        float2 pp = spos[t];
        float dx = pp.x - gx, dy = pp.y - gy;
        float power = -0.5f * (f1.x * dx * dx + f1.z * dy * dy) - f1.y * dx * dy;
        if (power <= 0.0f) {
            float alpha = fminf(0.99f, f1.w * __expf(power));
            if (alpha >= ALPHA_MIN) Tw *= (1.0f - alpha);
        }
    }
    scr[wave * 64 + lane] = Tw;
    __syncthreads();

    // Pass B: composite segment from exact prefix T0
    float T0 = 1.0f;
#pragma unroll
    for (int s = 0; s < NWAVE - 1; ++s) if (s < wave) T0 *= scr[s * 64 + lane];
    float T = T0, cr = 0.0f, cg = 0.0f, cb = 0.0f, dep = 0.0f;
    int cnt = 0;
    if (!__all(T0 <= T_EPS_C)) {
        for (int t = s0; t < s1; ++t) {
            float4 f1 = sf1[t];
            float4 f2v = sf2[t];
            float2 pp = spos[t];
            float dx = pp.x - gx, dy = pp.y - gy;
            float power = -0.5f * (f1.x * dx * dx + f1.z * dy * dy) - f1.y * dx * dy;
            if (power <= 0.0f) {
                float alpha = fminf(0.99f, f1.w * __expf(power));
                if (alpha >= ALPHA_MIN) {
                    if (T > T_EPS_C) {
                        float w = alpha * T;
                        cr += w * f2v.x; cg += w * f2v.y; cb += w * f2v.z;
                        dep += w * f2v.w;
                        cnt++;
                    }
                    T *= (1.0f - alpha);
                    if (__all(T <= T_EPS_C)) break;   // exact: final T from Tseg products
                }
            }
        }
    }
    accv[wave * 64 + lane] = make_float4(cr, cg, cb, dep);
    ((int*)lst)[wave * 64 + lane] = cnt;    // lst dead: overlay (1024 ints = 4 KB)
    __syncthreads();

    // ---- Final: wave 0 reduces 16 partials per pixel, adds bg, writes out ----
    if (tid < 64) {
        float crr = 0.0f, cgg = 0.0f, cbb = 0.0f, dpp = 0.0f, Tf = 1.0f;
        int cnt_t = 0;
        const int* an = (const int*)lst;
#pragma unroll
        for (int s = 0; s < NWAVE; ++s) {
            float4 a = accv[s * 64 + tid];
            crr += a.x; cgg += a.y; cbb += a.z; dpp += a.w;
            cnt_t += an[s * 64 + tid];
            Tf *= scr[s * 64 + tid];
        }
        crr += Tf * bg[0]; cgg += Tf * bg[1]; cbb += Tf * bg[2];

        int pid = ((tiley << 3) + (tid >> 3)) * W_IMG + (tilex << 3) + (tid & 7);
        out[0 * NPIX + pid] = crr;
        out[1 * NPIX + pid] = cgg;
        out[2 * NPIX + pid] = cbb;
        out[3 * NPIX + pid] = dpp;
        out[4 * NPIX + N_G + pid] = (float)cnt_t;
    }
}

extern "C" void kernel_launch(void* const* d_in, const int* in_sizes, int n_in,
                              void* d_out, int out_size, void* d_ws, size_t ws_size,
                              hipStream_t stream) {
    const float* bg      = (const float*)d_in[0];
    const float* means3D = (const float*)d_in[1];
    const float* opac    = (const float*)d_in[3];
    const float* colors  = (const float*)d_in[4];
    const float* scales  = (const float*)d_in[5];
    const float* rots    = (const float*)d_in[6];
    const float* viewm   = (const float*)d_in[7];
    const float* projm   = (const float*)d_in[8];

    float* out = (float*)d_out;
    float4* bb4 = (float4*)d_ws;                           // 32 KB
    float4* f1g = bb4 + N_G;                               // 32 KB
    float4* f2g = f1g + N_G;                               // 32 KB
    float* radii_out = out + 4 * NPIX;

    gs_pre<<<N_G / 64, 64, 0, stream>>>(means3D, opac, colors, scales, rots,
                                        viewm, projm, bb4, f1g, f2g, radii_out);
    gs_render<<<256, NTHR, 0, stream>>>(bb4, f1g, f2g, bg, out);
}

// Round 12
// 14.948 us; speedup vs baseline: 1.1605x; 1.1605x over previous
//
#include <hip/hip_runtime.h>
#include <math.h>

#define N_G   2048
#define W_IMG 128
#define H_IMG 128
#define NPIX  (W_IMG * H_IMG)
#define TANX  0.5f
#define TANY  0.5f
#define ALPHA_MIN (1.0f / 255.0f)
#define T_EPS_C 1e-4f
#define NTHR  1024
#define NWAVE 16
#define CAP   1024

// Full per-gaussian chain (exact reference math, fast intrinsics).
__device__ __forceinline__ void full_chain(int i,
        const float* __restrict__ means3D, const float* __restrict__ opac,
        const float* __restrict__ colors, const float* __restrict__ scales,
        const float* __restrict__ rots, const float* __restrict__ viewm,
        const float* __restrict__ projm,
        float4& f1, float4& f2, float& radf) {
    float mx = means3D[i * 3 + 0], my = means3D[i * 3 + 1], mz = means3D[i * 3 + 2];
    float pv0 = mx * viewm[0] + my * viewm[4] + mz * viewm[8]  + viewm[12];
    float pv1 = mx * viewm[1] + my * viewm[5] + mz * viewm[9]  + viewm[13];
    float tz  = mx * viewm[2] + my * viewm[6] + mz * viewm[10] + viewm[14];

    float qr = rots[i * 4 + 0], qx = rots[i * 4 + 1], qy = rots[i * 4 + 2], qz = rots[i * 4 + 3];
    float qn = __builtin_amdgcn_rsqf(qr * qr + qx * qx + qy * qy + qz * qz);
    qr *= qn; qx *= qn; qy *= qn; qz *= qn;
    float R[3][3] = {
        {1.0f - 2.0f * (qy * qy + qz * qz), 2.0f * (qx * qy - qr * qz), 2.0f * (qx * qz + qr * qy)},
        {2.0f * (qx * qy + qr * qz), 1.0f - 2.0f * (qx * qx + qz * qz), 2.0f * (qy * qz - qr * qx)},
        {2.0f * (qx * qz - qr * qy), 2.0f * (qy * qz + qr * qx), 1.0f - 2.0f * (qx * qx + qy * qy)}};

    float sc[3] = {scales[i * 3 + 0], scales[i * 3 + 1], scales[i * 3 + 2]};
    float M[3][3];
#pragma unroll
    for (int r = 0; r < 3; r++)
#pragma unroll
        for (int cx = 0; cx < 3; cx++) M[r][cx] = R[r][cx] * sc[cx];

    float Sg[3][3];
#pragma unroll
    for (int r = 0; r < 3; r++)
#pragma unroll
        for (int kk = 0; kk < 3; kk++)
            Sg[r][kk] = M[r][0] * M[kk][0] + M[r][1] * M[kk][1] + M[r][2] * M[kk][2];

    float T1[3][3];
#pragma unroll
    for (int j = 0; j < 3; j++)
#pragma unroll
        for (int l = 0; l < 3; l++)
            T1[j][l] = Sg[j][0] * viewm[0 * 4 + l] + Sg[j][1] * viewm[1 * 4 + l] + Sg[j][2] * viewm[2 * 4 + l];
    float Cc[3][3];
#pragma unroll
    for (int r = 0; r < 3; r++)
#pragma unroll
        for (int l = 0; l < 3; l++)
            Cc[r][l] = viewm[0 * 4 + r] * T1[0][l] + viewm[1 * 4 + r] * T1[1][l] + viewm[2 * 4 + r] * T1[2][l];

    const float fx = W_IMG / (2.0f * TANX), fy = H_IMG / (2.0f * TANY);
    float invtz = __builtin_amdgcn_rcpf(tz);
    float txl = fminf(fmaxf(pv0 * invtz, -1.3f * TANX), 1.3f * TANX) * tz;
    float tyl = fminf(fmaxf(pv1 * invtz, -1.3f * TANY), 1.3f * TANY) * tz;
    float a0 = fx * invtz, a2 = -fx * txl * invtz * invtz;
    float b1 = fy * invtz, b2 = -fy * tyl * invtz * invtz;

    float c00 = a0 * a0 * Cc[0][0] + 2.0f * a0 * a2 * Cc[0][2] + a2 * a2 * Cc[2][2];
    float c11 = b1 * b1 * Cc[1][1] + 2.0f * b1 * b2 * Cc[1][2] + b2 * b2 * Cc[2][2];
    float c01 = a0 * b1 * Cc[0][1] + a0 * b2 * Cc[0][2] + a2 * b1 * Cc[1][2] + a2 * b2 * Cc[2][2];

    float a = c00 + 0.3f, c = c11 + 0.3f, b = c01;
    float det = a * c - b * b;
    bool valid = (tz > 0.2f) && (det > 0.0f);
    float det_s = (det > 0.0f) ? det : 1.0f;
    float rdet = __builtin_amdgcn_rcpf(det_s);
    float conA = c * rdet, conB = -b * rdet, conC = a * rdet;
    float mid = 0.5f * (a + c);
    float lam = mid + __builtin_amdgcn_sqrtf(fmaxf(0.1f, mid * mid - det));
    radf = valid ? ceilf(3.0f * __builtin_amdgcn_sqrtf(lam)) : 0.0f;

    float op = opac[i];
    f1 = make_float4(conA, conB, conC, valid ? op : 0.0f);
    f2 = make_float4(colors[i * 3 + 0], colors[i * 3 + 1], colors[i * 3 + 2], tz);
}

// One block per 8x8 tile, 1024 threads, ~76 KB LDS, 5 barriers.
// Phase 0+A FUSED: per thread, cheap conservative bound for 2 gaussians,
//                  immediate tile test, wave-aggregated atomic append of
//                  (key=(bits(tz)<<16)|idx, pos). No full-bbox LDS array.
// Phase B: rank by packed u64 key (1 cmp per entry); full-chain candidates;
//          scatter into sorted LDS SoA. Radii: 8 exact chains per block.
// Phase C: segmented composite over 16 waves (exact two-pass prefix products).
__global__ __launch_bounds__(NTHR) void gs_fused(const float* __restrict__ means3D,
                                                 const float* __restrict__ opac,
                                                 const float* __restrict__ colors,
                                                 const float* __restrict__ scales,
                                                 const float* __restrict__ rots,
                                                 const float* __restrict__ viewm,
                                                 const float* __restrict__ projm,
                                                 const float* __restrict__ bg,
                                                 float* __restrict__ out) {
    __shared__ unsigned long long ckey[CAP];   // (bits(tz)<<16)|idx       8 KB
    __shared__ float2 cpos[CAP];               // px,py; later cnt overlay 8 KB
    __shared__ float4 sf1[CAP];                // sorted conic+op         16 KB
    __shared__ float4 sf2[CAP];                // sorted color+tz         16 KB
    __shared__ float2 spos[CAP];               // sorted px,py             8 KB
    __shared__ float  tseg[NTHR];              // Tseg                     4 KB
    __shared__ float4 accv[NTHR];              // pass-B partials         16 KB
    __shared__ int s_count;

    int tid = threadIdx.x;
    int bid = blockIdx.x;
    float* radii_out = out + 4 * NPIX;
    if (tid == 0) s_count = 0;
    __syncthreads();

    int tilex = bid & 15, tiley = bid >> 4;
    int wave = tid >> 6, lane = tid & 63;
    float tx0 = (float)(tilex << 3), ty0 = (float)(tiley << 3);
    float tx1 = tx0 + 7.0f, ty1 = ty0 + 7.0f;

    // view-rotation norm bound: lambda_max(W^T W) <= ||W||_1 * ||W||_inf
    float cs0 = fabsf(viewm[0]) + fabsf(viewm[4]) + fabsf(viewm[8]);
    float cs1 = fabsf(viewm[1]) + fabsf(viewm[5]) + fabsf(viewm[9]);
    float cs2 = fabsf(viewm[2]) + fabsf(viewm[6]) + fabsf(viewm[10]);
    float rs0 = fabsf(viewm[0]) + fabsf(viewm[1]) + fabsf(viewm[2]);
    float rs1 = fabsf(viewm[4]) + fabsf(viewm[5]) + fabsf(viewm[6]);
    float rs2 = fabsf(viewm[8]) + fabsf(viewm[9]) + fabsf(viewm[10]);
    float wb2 = fmaxf(cs0, fmaxf(cs1, cs2)) * fmaxf(rs0, fmaxf(rs1, rs2));

    // ---- Phase 0+A: cheap bound + cull + append, 2 gaussians per thread ----
#pragma unroll
    for (int cc = 0; cc < 2; cc++) {
        int i = (wave * 2 + cc) * 64 + lane;
        float mx = means3D[i * 3 + 0], my = means3D[i * 3 + 1], mz = means3D[i * 3 + 2];
        float pv0 = mx * viewm[0] + my * viewm[4] + mz * viewm[8]  + viewm[12];
        float pv1 = mx * viewm[1] + my * viewm[5] + mz * viewm[9]  + viewm[13];
        float tz  = mx * viewm[2] + my * viewm[6] + mz * viewm[10] + viewm[14];

        float ph[4];
#pragma unroll
        for (int j = 0; j < 4; j++)
            ph[j] = mx * projm[0 * 4 + j] + my * projm[1 * 4 + j] + mz * projm[2 * 4 + j] + projm[3 * 4 + j];
        float inv_w = __builtin_amdgcn_rcpf(ph[3] + 1e-7f);
        float px = ((ph[0] * inv_w + 1.0f) * (float)W_IMG - 1.0f) * 0.5f;
        float py = ((ph[1] * inv_w + 1.0f) * (float)H_IMG - 1.0f) * 0.5f;

        float s0 = scales[i * 3 + 0], s1 = scales[i * 3 + 1], s2 = scales[i * 3 + 2];
        float smax2 = fmaxf(s0 * s0, fmaxf(s1 * s1, s2 * s2));
        float op = opac[i];
        float L = __logf(255.0f * op);

        float invtz = __builtin_amdgcn_rcpf(tz);
        float ux = pv0 * invtz, uy = pv1 * invtz;
        float u2x = fminf(ux * ux, 0.4225f);     // (1.3*TANX)^2
        float u2y = fminf(uy * uy, 0.4225f);
        float f2 = (W_IMG / (2.0f * TANX)) * invtz;   // fx == fy == 128
        f2 *= f2;
        float sw = smax2 * wb2;
        float abound = f2 * (1.0f + u2x) * sw + 0.3f;   // >= a = cov2d_xx + 0.3
        float cbound = f2 * (1.0f + u2y) * sw + 0.3f;   // >= c = cov2d_yy + 0.3
        float exb = __builtin_amdgcn_sqrtf(2.0f * L * abound) * 1.03f + 0.05f;
        float eyb = __builtin_amdgcn_sqrtf(2.0f * L * cbound) * 1.03f + 0.05f;
        bool ok = (tz > 0.2f) && (L > 0.0f);

        bool pred = ok && (px >= tx0 - exb) && (px <= tx1 + exb) &&
                          (py >= ty0 - eyb) && (py <= ty1 + eyb);
        unsigned long long m = __ballot(pred);
        int n = (int)__popcll(m);
        int base = 0;
        if (lane == 0 && n) base = atomicAdd(&s_count, n);
        base = __shfl(base, 0);
        if (pred) {
            int slot = base + (int)__popcll(m & ((1ull << lane) - 1ull));
            if (slot < CAP) {
                // tz > 0.2 positive -> IEEE bit order == float order; idx tiebreak
                unsigned int tzb = __float_as_uint(tz);
                ckey[slot] = ((unsigned long long)tzb << 16) | (unsigned int)i;
                cpos[slot] = make_float2(px, py);
            }
        }
    }
    __syncthreads();
    int c = min(s_count, CAP);

    // ---- Phase B: rank by u64 key + full-chain candidate + scatter ----
    for (int t = tid; t < c; t += NTHR) {
        unsigned long long mykey = ckey[t];
        int rank = 0;
        int j = 0;
        const ulonglong2* k2 = (const ulonglong2*)ckey;
        for (; j + 2 <= c; j += 2) {
            ulonglong2 v = k2[j >> 1];
            rank += (v.x < mykey);
            rank += (v.y < mykey);
        }
        for (; j < c; j++) rank += (ckey[j] < mykey);

        int gi = (int)(mykey & 0xFFFFull);
        float4 f1, f2v; float radf;
        full_chain(gi, means3D, opac, colors, scales, rots, viewm, projm, f1, f2v, radf);
        sf1[rank] = f1;
        sf2[rank] = f2v;
        spos[rank] = cpos[t];
    }
    // radii: this block's 8 gaussians, exact
    if (tid < 8) {
        int g8 = bid * 8 + tid;
        float4 d1, d2; float radf;
        full_chain(g8, means3D, opac, colors, scales, rots, viewm, projm, d1, d2, radf);
        radii_out[g8] = (float)(int)radf;
    }
    __syncthreads();   // cpos dead from here; reused as cnt overlay

    // ---- Phase C: segmented composite over 16 waves ----
    float gx = (float)((tilex << 3) + (lane & 7));
    float gy = (float)((tiley << 3) + (lane >> 3));
    int seglen = (c + NWAVE - 1) / NWAVE;
    int s0 = wave * seglen;
    int s1 = min(c, s0 + seglen);

    // Pass A: per-segment transmittance product (alpha-only; matches cumprod)
    float Tw = 1.0f;
    for (int t = s0; t < s1; ++t) {
        float4 f1 = sf1[t];
        float2 pp = spos[t];
        float dx = pp.x - gx, dy = pp.y - gy;
        float power = -0.5f * (f1.x * dx * dx + f1.z * dy * dy) - f1.y * dx * dy;
        if (power <= 0.0f) {
            float alpha = fminf(0.99f, f1.w * __expf(power));
            if (alpha >= ALPHA_MIN) Tw *= (1.0f - alpha);
        }
    }
    tseg[wave * 64 + lane] = Tw;
    __syncthreads();

    // Pass B: composite segment from exact prefix T0
    float T0 = 1.0f;
#pragma unroll
    for (int s = 0; s < NWAVE - 1; ++s) if (s < wave) T0 *= tseg[s * 64 + lane];
    float T = T0, cr = 0.0f, cg = 0.0f, cb = 0.0f, dep = 0.0f;
    int cnt = 0;
    if (!__all(T0 <= T_EPS_C)) {
        for (int t = s0; t < s1; ++t) {
            float4 f1 = sf1[t];
            float4 f2v = sf2[t];
            float2 pp = spos[t];
            float dx = pp.x - gx, dy = pp.y - gy;
            float power = -0.5f * (f1.x * dx * dx + f1.z * dy * dy) - f1.y * dx * dy;
            if (power <= 0.0f) {
                float alpha = fminf(0.99f, f1.w * __expf(power));
                if (alpha >= ALPHA_MIN) {
                    if (T > T_EPS_C) {
                        float w = alpha * T;
                        cr += w * f2v.x; cg += w * f2v.y; cb += w * f2v.z;
                        dep += w * f2v.w;
                        cnt++;
                    }
                    T *= (1.0f - alpha);
                    if (__all(T <= T_EPS_C)) break;   // exact: final T from Tseg products
                }
            }
        }
    }
    accv[wave * 64 + lane] = make_float4(cr, cg, cb, dep);
    ((int*)cpos)[wave * 64 + lane] = cnt;   // cpos overlay (1024 ints)
    __syncthreads();

    // ---- Final: wave 0 reduces 16 partials per pixel, adds bg, writes out ----
    if (tid < 64) {
        float crr = 0.0f, cgg = 0.0f, cbb = 0.0f, dpp = 0.0f, Tf = 1.0f;
        int cnt_t = 0;
        const int* an = (const int*)cpos;
#pragma unroll
        for (int s = 0; s < NWAVE; ++s) {
            float4 a = accv[s * 64 + tid];
            crr += a.x; cgg += a.y; cbb += a.z; dpp += a.w;
            cnt_t += an[s * 64 + tid];
            Tf *= tseg[s * 64 + tid];
        }
        crr += Tf * bg[0]; cgg += Tf * bg[1]; cbb += Tf * bg[2];

        int pid = ((tiley << 3) + (tid >> 3)) * W_IMG + (tilex << 3) + (tid & 7);
        out[0 * NPIX + pid] = crr;
        out[1 * NPIX + pid] = cgg;
        out[2 * NPIX + pid] = cbb;
        out[3 * NPIX + pid] = dpp;
        out[4 * NPIX + N_G + pid] = (float)cnt_t;
    }
}

extern "C" void kernel_launch(void* const* d_in, const int* in_sizes, int n_in,
                              void* d_out, int out_size, void* d_ws, size_t ws_size,
                              hipStream_t stream) {
    const float* bg      = (const float*)d_in[0];
    const float* means3D = (const float*)d_in[1];
    const float* opac    = (const float*)d_in[3];
    const float* colors  = (const float*)d_in[4];
    const float* scales  = (const float*)d_in[5];
    const float* rots    = (const float*)d_in[6];
    const float* viewm   = (const float*)d_in[7];
    const float* projm   = (const float*)d_in[8];

    gs_fused<<<256, NTHR, 0, stream>>>(means3D, opac, colors, scales, rots,
                                       viewm, projm, bg, (float*)d_out);
}